// Round 7
// baseline (1136.898 us; speedup 1.0000x reference)
//
#include <hip/hip_runtime.h>
#include <hip/hip_bf16.h>
#include <stdint.h>

#define HH 128
#define WW 128
#define NIMG 32
#define CH 16
#define TX 32            // tile width
#define TY 16            // tile height
#define LWX 36           // 32 + 2*2 halo
#define LWY 20           // 16 + 2*2 halo
#define LA (LWX * LWY)   // 720 floats per channel plane
#define NUM_ITER 30
#define THR 0.1f
#define HWSZ (HH * WW)

#define PSTR 52                         // P/H row stride in bf16 elems (104 B, 8B-aligned)
#define CS_BYTES (17 * LA * 4)          // 48960 B: 17 planes (phases A-D1)
#define SMEM_BYTES (512 * PSTR * 2)     // 53248 B (Ph overlay dominates) -> 3 blocks/CU

typedef __attribute__((ext_vector_type(8))) short bf16x8;
typedef __attribute__((ext_vector_type(4))) float f32x4;
typedef __attribute__((ext_vector_type(4))) short sh4;

// hardware RNE f32->bf16
__device__ __forceinline__ unsigned short f2bf(float x) {
    return __builtin_bit_cast(unsigned short, __float2bfloat16(x));
}
__device__ __forceinline__ float bf2f(unsigned short h) {
    union { unsigned u; float f; } v; v.u = ((unsigned)h) << 16; return v.f;
}
__device__ __forceinline__ bf16x8 mk8(sh4 a, sh4 b) {
    bf16x8 r;
    r[0] = a.x; r[1] = a.y; r[2] = a.z; r[3] = a.w;
    r[4] = b.x; r[5] = b.y; r[6] = b.z; r[7] = b.w;
    return r;
}
__device__ __forceinline__ sh4 ld4(const unsigned short* p) {
    return *(const sh4*)p;
}
// 9-point max as v_max3-fusable triples
__device__ __forceinline__ float max9(const float* p, int idx, int stride) {
    float a = fmaxf(fmaxf(p[idx - stride - 1], p[idx - stride]), p[idx - stride + 1]);
    float b = fmaxf(fmaxf(p[idx - 1],          p[idx]),          p[idx + 1]);
    float c = fmaxf(fmaxf(p[idx + stride - 1], p[idx + stride]), p[idx + stride + 1]);
    return fmaxf(fmaxf(a, b), c);
}

// ---------------- weight prepack: bf16 hi/lo split, row-major ----
__global__ void prepack(const float* __restrict__ w1, const float* __restrict__ w2,
                        unsigned short* __restrict__ w1h, unsigned short* __restrict__ w1l,
                        unsigned short* __restrict__ w2h, unsigned short* __restrict__ w2l) {
    int i = threadIdx.x;
    for (int k = i; k < 48 * 48; k += 256) {
        float f = w1[k];
        unsigned short h = f2bf(f);
        w1h[k] = h;
        w1l[k] = f2bf(f - bf2f(h));
    }
    for (int k = i; k < 16 * 48; k += 256) {
        float f = w2[k];
        unsigned short h = f2bf(f);
        w2h[k] = h;
        w2l[k] = f2bf(f - bf2f(h));
    }
}

// perception: p[0..15]=center, p[16..31]=sobel-x, p[32..47]=sobel-y
__device__ __forceinline__ void perception_at(const float* cs, int base, float* p) {
#pragma unroll
    for (int c = 0; c < CH; ++c) {
        const float* cc = cs + c * LA;
        float c00 = cc[base - LWX - 1], c01 = cc[base - LWX], c02 = cc[base - LWX + 1];
        float c10 = cc[base - 1],       c11 = cc[base],       c12 = cc[base + 1];
        float c20 = cc[base + LWX - 1], c21 = cc[base + LWX], c22 = cc[base + LWX + 1];
        p[c]      = c11;
        p[16 + c] = (c02 - c00 + 2.0f * (c12 - c10) + c22 - c20) * 0.125f;
        p[32 + c] = (c20 - c00 + 2.0f * (c21 - c01) + c22 - c02) * 0.125f;
    }
}

// ---------------- one fused CA step (MFMA matmuls, R7) ----------------
// R7 vs R6 (single change): D5 store path. Old: 16 scalar dword stores/lane,
// each inst scattering 4x64-B segments; L2 at capacity (4 MB cout + 4 MB cin
// per XCD) evicts partially-dirty lines -> RMW -> WRITE_SIZE 84.9 MB vs 33
// ideal. New: wave-private LDS bounce ([16ch][68] floats in this wave's own
// Ph slice, same-wave in-order DS -> no barrier) + f32x4 read-back with
// (ch,row,xchunk) lane mapping: every store inst writes 8 complete 128-B
// lines. 16 stores/lane -> 4. Bit-exact reordering.
__global__ __launch_bounds__(512, 6) void step_kernel(
    const float* __restrict__ inp, const float* __restrict__ cin,
    float* __restrict__ cout,
    const uint8_t* __restrict__ pre_in, uint8_t* __restrict__ pre_out,
    const unsigned short* __restrict__ w1h_, const unsigned short* __restrict__ w1l_,
    const unsigned short* __restrict__ w2h_, const unsigned short* __restrict__ w2l_,
    int gate, int first) {

    __shared__ __align__(16) char smem[SMEM_BYTES];
    float* cs = (float*)smem;                       // 17 planes x 720 floats
    unsigned short* Ph = (unsigned short*)smem;     // [512][PSTR] bf16 (overlays cs)

    const int tid = threadIdx.x;
    const int tx2 = tid & 31, ty2 = tid >> 5;       // pixel within 32x16 tile
    const int lane = tid & 63;
    const int wv = tid >> 6;            // wave id: pixels [64*wv, 64*wv+64) = rows 2wv,2wv+1
    const int px = lane & 15;           // col within 16-tile
    const int kc = lane >> 4;           // k-chunk id (0..3)

    // ---- XCD-aware decode: wgid%8 = XCD; each XCD owns 4 whole images ----
    const int wgid = blockIdx.x;
    const int xcd = wgid & 7;
    const int s   = wgid >> 3;              // 0..127 per XCD
    const int n   = (xcd << 2) + (s >> 5);  // image
    const int t_  = s & 31;                 // tile within image (4x8)
    const int bx = (t_ & 3) * TX;
    const int by = (t_ >> 2) * TY;

    const float* cbase = cin + (size_t)n * CH * HWSZ;
    const float* ibase = inp + (size_t)n * 10 * HWSZ;
    const uint8_t* pbase = pre_in + (size_t)n * HWSZ;

    // ---- hoisted coords: full 36x20 positions (raw ch0), two per thread ----
    const int lyA = tid / 36, lxA = tid % 36;
    const int gyA = by + lyA - 2, gxA = bx + lxA - 2;
    const bool okA = ((unsigned)gyA < HH) && ((unsigned)gxA < WW);
    const int offA = gyA * WW + gxA;

    const int rB = tid + 512;                  // valid when tid < 208 (720 total)
    const int lyB = rB / 36, lxB = rB % 36;
    const int gyB = by + lyB - 2, gxB = bx + lxB - 2;
    const bool okB = ((unsigned)gyB < HH) && ((unsigned)gxB < WW);
    const int offB = gyB * WW + gxB;
    const bool hasA2 = (tid < 208);

    // ---- hoisted coords: 34x18 gate-region positions, two per thread ----
    const int j0 = tid;                        // always < 612
    const int jy0 = j0 / 34, jx0 = j0 % 34;
    const int gy0 = by + jy0 - 1, gx0 = bx + jx0 - 1;
    const bool ok0 = ((unsigned)gy0 < HH) && ((unsigned)gx0 < WW);
    const int goff0 = gy0 * WW + gx0;
    const int lpos0 = (jy0 + 1) * LWX + (jx0 + 1);

    const int j1 = tid + 512;                  // valid when tid < 100 (612 total)
    const int jy1 = j1 / 34, jx1 = j1 % 34;
    const int gy1 = by + jy1 - 1, gx1 = bx + jx1 - 1;
    const bool ok1 = ((unsigned)gy1 < HH) && ((unsigned)gx1 < WW);
    const int goff1 = gy1 * WW + gx1;
    const int lpos1 = (jy1 + 1) * LWX + (jx1 + 1);
    const bool hasB = (tid < 100);

    // ---- A: stage raw ch0 (plane 16) AND pre-issue all global loads ----
    // first=1: read from inp with the init mapping (ch0 = 1-inp0).
    if (first) {
        cs[CH * LA + tid] = okA ? 1.0f - ibase[offA] : 0.0f;
        if (hasA2) cs[CH * LA + rB] = okB ? 1.0f - ibase[offB] : 0.0f;
    } else {
        cs[CH * LA + tid] = okA ? cbase[offA] : 0.0f;
        if (hasA2) cs[CH * LA + rB] = okB ? cbase[offB] : 0.0f;
    }

    float st0[CH - 1];
    float st1[CH - 1];
    int pv0 = 1, pv1 = 1;
    if (first) {
#pragma unroll
        for (int c = 1; c < CH; ++c)
            st0[c - 1] = (c <= 10 && ok0) ? ibase[(c - 1) * HWSZ + goff0] : 0.0f;
        if (hasB) {
#pragma unroll
            for (int c = 1; c < CH; ++c)
                st1[c - 1] = (c <= 10 && ok1) ? ibase[(c - 1) * HWSZ + goff1] : 0.0f;
        }
    } else {
        {
            const float* gp = cbase + goff0;
#pragma unroll
            for (int c = 1; c < CH; ++c) st0[c - 1] = ok0 ? gp[c * HWSZ] : 0.0f;
        }
        if (gate) pv0 = ok0 ? (int)pbase[goff0] : 0;
        if (hasB) {
            const float* gp = cbase + goff1;
#pragma unroll
            for (int c = 1; c < CH; ++c) st1[c - 1] = ok1 ? gp[c * HWSZ] : 0.0f;
            if (gate) pv1 = ok1 ? (int)pbase[goff1] : 0;
        }
    }
    __syncthreads();   // sync1

    // ---- B+C fused: gate from raw plane 16; gated writes to planes 0..15 ----
    {
        const float* rp = cs + CH * LA;
        float pm = max9(rp, lpos0, LWX);
        float g0 = 1.0f;
        if (gate) g0 = (pv0 && pm > THR) ? 1.0f : 0.0f;
        cs[lpos0] = rp[lpos0] * g0;
#pragma unroll
        for (int c = 1; c < CH; ++c) cs[c * LA + lpos0] = st0[c - 1] * g0;
    }
    if (hasB) {
        const float* rp = cs + CH * LA;
        float pm = max9(rp, lpos1, LWX);
        float g1 = 1.0f;
        if (gate) g1 = (pv1 && pm > THR) ? 1.0f : 0.0f;
        cs[lpos1] = rp[lpos1] * g1;
#pragma unroll
        for (int c = 1; c < CH; ++c) cs[c * LA + lpos1] = st1[c - 1] * g1;
    }
    __syncthreads();   // sync2

    // ---- D1: pre(i) bits + per-thread perception + residual grab (reads cs) ----
    const int base = (ty2 + 2) * LWX + (tx2 + 2);
    {
        float pm = max9(cs, base, LWX);
        pre_out[(size_t)n * HWSZ + (size_t)(by + ty2) * WW + (bx + tx2)] = (pm > THR) ? 1 : 0;
    }

    float p[48];
    perception_at(cs, base, p);

    // residual for this lane's D5 output assignment: pixel pix=64wv+16t+px,
    // channel 4kc+r -- gated fp32 state from cs, read before the Ph overlay.
    float res[4][4];
#pragma unroll
    for (int t = 0; t < 4; ++t) {
        const int pix = 64 * wv + 16 * t + px;
        const int lp = ((pix >> 5) + 2) * LWX + ((pix & 31) + 2);
#pragma unroll
        for (int r = 0; r < 4; ++r)
            res[t][r] = cs[(4 * kc + r) * LA + lp];
    }
    __syncthreads();   // sync3: all cs reads done; Ph may now overlay cs

    // ---- D2: p -> bf16 hi into LDS (row = tid = pixel; wave-private rows) ----
    {
        unsigned short* hrow = Ph + tid * PSTR;
#pragma unroll
        for (int j = 0; j < 12; ++j) {
            sh4 hv;
            hv.x = (short)f2bf(p[4 * j + 0]);
            hv.y = (short)f2bf(p[4 * j + 1]);
            hv.z = (short)f2bf(p[4 * j + 2]);
            hv.w = (short)f2bf(p[4 * j + 3]);
            *(sh4*)(hrow + 4 * j) = hv;
        }
    }
    // no barrier: D3 B-reads are wave-private rows, DS pipe in-order per wave

    // ---- D3: h = relu(w1 x P) via MFMA (2-product: (w1h+w1l) x Phi) ----
    const sh4 z4 = (sh4)0;
    const bf16x8 zero8 = mk8(z4, z4);

    f32x4 acc[3][4];
#pragma unroll
    for (int m = 0; m < 3; ++m)
#pragma unroll
        for (int t = 0; t < 4; ++t) acc[m][t] = 0.0f;

#pragma unroll
    for (int m = 0; m < 3; ++m) {
        const unsigned short* ah = w1h_ + (16 * m + px) * 48;
        const unsigned short* al = w1l_ + (16 * m + px) * 48;
        bf16x8 Ah1 = mk8(ld4(ah + 8 * kc), ld4(ah + 8 * kc + 4));
        bf16x8 Ah2 = mk8(ld4(ah + 32 + 8 * kc), ld4(ah + 36 + 8 * kc));  // padded buf; garbage for kc>=2 ok (B=0)
        bf16x8 Al1 = mk8(ld4(al + 8 * kc), ld4(al + 8 * kc + 4));
        bf16x8 Al2 = mk8(ld4(al + 32 + 8 * kc), ld4(al + 36 + 8 * kc));
#pragma unroll
        for (int t = 0; t < 4; ++t) {
            const int pix = 64 * wv + 16 * t + px;
            const unsigned short* bh = Ph + pix * PSTR;
            bf16x8 Bh1 = mk8(ld4(bh + 8 * kc), ld4(bh + 8 * kc + 4));
            bf16x8 Bh2 = (kc < 2) ? mk8(ld4(bh + 32 + 8 * kc), ld4(bh + 36 + 8 * kc)) : zero8;
            f32x4 a = acc[m][t];
            a = __builtin_amdgcn_mfma_f32_16x16x32_bf16(Al1, Bh1, a, 0, 0, 0);
            a = __builtin_amdgcn_mfma_f32_16x16x32_bf16(Al2, Bh2, a, 0, 0, 0);
            a = __builtin_amdgcn_mfma_f32_16x16x32_bf16(Ah1, Bh1, a, 0, 0, 0);
            a = __builtin_amdgcn_mfma_f32_16x16x32_bf16(Ah2, Bh2, a, 0, 0, 0);
            acc[m][t] = a;
        }
    }
    // no barrier: D4 writes the same wave-private rows D3 just read

    // ---- D4: h = relu(acc) -> bf16, overlaying Ph. lane holds q=16m+4kc+r ----
#pragma unroll
    for (int t = 0; t < 4; ++t) {
        const int pix = 64 * wv + 16 * t + px;
        unsigned short* hrow = Ph + pix * PSTR;
#pragma unroll
        for (int m = 0; m < 3; ++m) {
            f32x4 a = acc[m][t];
            sh4 hv;
            hv.x = (short)f2bf(fmaxf(a[0], 0.0f));
            hv.y = (short)f2bf(fmaxf(a[1], 0.0f));
            hv.z = (short)f2bf(fmaxf(a[2], 0.0f));
            hv.w = (short)f2bf(fmaxf(a[3], 0.0f));
            *(sh4*)(hrow + 16 * m + 4 * kc) = hv;
        }
    }
    // no barrier: D5 reads the same wave-private rows

    // ---- D5: cur = (w2h+w2l) x H + res; coalesced store via LDS bounce ----
    {
        const unsigned short* ah = w2h_ + px * 48;
        const unsigned short* al = w2l_ + px * 48;
        bf16x8 A2h1 = mk8(ld4(ah + 8 * kc), ld4(ah + 8 * kc + 4));
        bf16x8 A2h2 = mk8(ld4(ah + 32 + 8 * kc), ld4(ah + 36 + 8 * kc));
        bf16x8 A2l1 = mk8(ld4(al + 8 * kc), ld4(al + 8 * kc + 4));
        bf16x8 A2l2 = mk8(ld4(al + 32 + 8 * kc), ld4(al + 36 + 8 * kc));

        f32x4 q[4];
#pragma unroll
        for (int t = 0; t < 4; ++t) q[t] = 0.0f;
#pragma unroll
        for (int t = 0; t < 4; ++t) {
            const int pix = 64 * wv + 16 * t + px;
            const unsigned short* bh = Ph + pix * PSTR;
            bf16x8 B1 = mk8(ld4(bh + 8 * kc), ld4(bh + 8 * kc + 4));
            bf16x8 B2 = (kc < 2) ? mk8(ld4(bh + 32 + 8 * kc), ld4(bh + 36 + 8 * kc)) : zero8;
            f32x4 a = q[t];
            a = __builtin_amdgcn_mfma_f32_16x16x32_bf16(A2l1, B1, a, 0, 0, 0);
            a = __builtin_amdgcn_mfma_f32_16x16x32_bf16(A2l2, B2, a, 0, 0, 0);
            a = __builtin_amdgcn_mfma_f32_16x16x32_bf16(A2h1, B1, a, 0, 0, 0);
            a = __builtin_amdgcn_mfma_f32_16x16x32_bf16(A2h2, B2, a, 0, 0, 0);
            q[t] = a;
        }

        // D5b: scatter q+res into wave-private [16ch][68] float buffer in this
        // wave's own Ph slice (H reads above are same-wave -> in-order DS, no
        // barrier), then vector-read-back so each global store inst writes
        // 8 complete 128-B lines.
        float* cb = (float*)(smem + wv * (64 * PSTR * 2));   // 4352 B used of 6656
#pragma unroll
        for (int t = 0; t < 4; ++t) {
            const int l = 16 * t + px;               // local pixel 0..63
#pragma unroll
            for (int r = 0; r < 4; ++r)
                cb[(4 * kc + r) * 68 + l] = q[t][r] + res[t][r];
        }
        float* ob = cout + (size_t)n * CH * HWSZ;
        const int l8 = lane & 7;                      // x-chunk (4 floats)
        const int c8 = lane >> 3;                     // ch low bits (0..7)
#pragma unroll
        for (int j = 0; j < 2; ++j)
#pragma unroll
            for (int h = 0; h < 2; ++h) {
                const int ch = 8 * h + c8;
                f32x4 v = *(const f32x4*)&cb[ch * 68 + j * 32 + l8 * 4];
                *(f32x4*)&ob[(size_t)ch * HWSZ +
                             (size_t)(by + 2 * wv + j) * WW + (bx + 4 * l8)] = v;
            }
    }
}

// ---------------- final: apply gate(30), emit channels 1..10 ----------------
__global__ __launch_bounds__(256) void final_kernel(
    const float* __restrict__ cur, const uint8_t* __restrict__ pre,
    float* __restrict__ out) {
    int i = blockIdx.x * 256 + threadIdx.x;        // over NIMG*H*W
    if (i >= NIMG * HWSZ) return;
    int x = i % WW, y = (i / WW) % HH, n = i / HWSZ;
    const float* c0 = cur + (size_t)n * CH * HWSZ;
    float pm = -1e30f;
    for (int dy = -1; dy <= 1; ++dy) {
        int yy = y + dy;
        if ((unsigned)yy >= HH) continue;
        for (int dx = -1; dx <= 1; ++dx) {
            int xx = x + dx;
            if ((unsigned)xx >= WW) continue;
            pm = fmaxf(pm, c0[yy * WW + xx]);
        }
    }
    const bool alive = pre[i] && (pm > THR);
    float* ob = out + (size_t)n * 10 * HWSZ + y * WW + x;
#pragma unroll
    for (int k = 1; k <= 10; ++k)
        ob[(k - 1) * HWSZ] = alive ? c0[k * HWSZ + y * WW + x] : 0.0f;
}

extern "C" void kernel_launch(void* const* d_in, const int* in_sizes, int n_in,
                              void* d_out, int out_size, void* d_ws, size_t ws_size,
                              hipStream_t stream) {
    const float* inp = (const float*)d_in[0];
    const float* w1  = (const float*)d_in[1];
    const float* w2  = (const float*)d_in[2];
    float* out = (float*)d_out;

    const size_t SE = (size_t)NIMG * CH * HWSZ;    // 8,388,608 floats
    float* bufA = (float*)d_ws;
    float* bufB = bufA + SE;
    uint8_t* bitsA = (uint8_t*)(bufB + SE);
    uint8_t* bitsB = bitsA + (size_t)NIMG * HWSZ;
    // weight fragments (bf16), padded +32 shorts so chunk-2 A reads stay in-bounds
    unsigned short* w1h = (unsigned short*)(bitsB + (size_t)NIMG * HWSZ);
    unsigned short* w1l = w1h + (48 * 48 + 32);
    unsigned short* w2h = w1l + (48 * 48 + 32);
    unsigned short* w2l = w2h + (16 * 48 + 32);

    prepack<<<1, 256, 0, stream>>>(w1, w2, w1h, w1l, w2h, w2l);

    const int nblk = NIMG * (HH / TY) * (WW / TX);   // 1024, 1-D swizzled grid
    float* src = bufB;      // dummy on first iter (first=1 reads inp)
    float* dst = bufA;
    uint8_t* pin = bitsB;   // unused on first iter (gate=0)
    uint8_t* pout = bitsA;
    for (int it = 0; it < NUM_ITER; ++it) {
        step_kernel<<<nblk, 512, 0, stream>>>(inp, src, dst, pin, pout,
                                              w1h, w1l, w2h, w2l,
                                              it == 0 ? 0 : 1, it == 0 ? 1 : 0);
        float* t = src; src = dst; dst = t;
        uint8_t* tb = pin; pin = pout; pout = tb;
    }
    // after loop: src = cur(30), pin = pre(30) bits
    final_kernel<<<(NIMG * HWSZ + 255) / 256, 256, 0, stream>>>(src, pin, out);
}

// Round 8
// 871.117 us; speedup vs baseline: 1.3051x; 1.3051x over previous
//
#include <hip/hip_runtime.h>
#include <hip/hip_bf16.h>
#include <stdint.h>

#define HH 128
#define WW 128
#define NIMG 32
#define CH 16
#define TX 32            // tile width
#define TY 8             // tile height
#define LWX 36           // 32 + 2*2 halo
#define LWY 12           // 8 + 2*2 halo
#define LA (LWX * LWY)   // 432 floats per channel plane
#define NUM_ITER 30
#define THR 0.1f
#define HWSZ (HH * WW)

#define PSTR 52                        // P/H row stride in bf16 elems (104 B)
#define CS_BYTES (17 * LA * 4)         // 29376 B: 17 planes (phases A-D1)
#define SMEM_BYTES CS_BYTES            // Ph overlay (26624) fits inside -> 5 blocks/CU

typedef __attribute__((ext_vector_type(8))) short bf16x8;
typedef __attribute__((ext_vector_type(4))) float f32x4;
typedef __attribute__((ext_vector_type(4))) short sh4;

// hardware RNE f32->bf16
__device__ __forceinline__ unsigned short f2bf(float x) {
    return __builtin_bit_cast(unsigned short, __float2bfloat16(x));
}
__device__ __forceinline__ float bf2f(unsigned short h) {
    union { unsigned u; float f; } v; v.u = ((unsigned)h) << 16; return v.f;
}
__device__ __forceinline__ bf16x8 mk8(sh4 a, sh4 b) {
    bf16x8 r;
    r[0] = a.x; r[1] = a.y; r[2] = a.z; r[3] = a.w;
    r[4] = b.x; r[5] = b.y; r[6] = b.z; r[7] = b.w;
    return r;
}
__device__ __forceinline__ sh4 ld4(const unsigned short* p) {
    return *(const sh4*)p;
}
// 9-point max as v_max3-fusable triples
__device__ __forceinline__ float max9(const float* p, int idx, int stride) {
    float a = fmaxf(fmaxf(p[idx - stride - 1], p[idx - stride]), p[idx - stride + 1]);
    float b = fmaxf(fmaxf(p[idx - 1],          p[idx]),          p[idx + 1]);
    float c = fmaxf(fmaxf(p[idx + stride - 1], p[idx + stride]), p[idx + stride + 1]);
    return fmaxf(fmaxf(a, b), c);
}

// ---------------- weight prepack: bf16 hi/lo split, row-major ----
__global__ void prepack(const float* __restrict__ w1, const float* __restrict__ w2,
                        unsigned short* __restrict__ w1h, unsigned short* __restrict__ w1l,
                        unsigned short* __restrict__ w2h, unsigned short* __restrict__ w2l) {
    int i = threadIdx.x;
    for (int k = i; k < 48 * 48; k += 256) {
        float f = w1[k];
        unsigned short h = f2bf(f);
        w1h[k] = h;
        w1l[k] = f2bf(f - bf2f(h));
    }
    for (int k = i; k < 16 * 48; k += 256) {
        float f = w2[k];
        unsigned short h = f2bf(f);
        w2h[k] = h;
        w2l[k] = f2bf(f - bf2f(h));
    }
}

// perception: p[0..15]=center, p[16..31]=sobel-x, p[32..47]=sobel-y
__device__ __forceinline__ void perception_at(const float* cs, int base, float* p) {
#pragma unroll
    for (int c = 0; c < CH; ++c) {
        const float* cc = cs + c * LA;
        float c00 = cc[base - LWX - 1], c01 = cc[base - LWX], c02 = cc[base - LWX + 1];
        float c10 = cc[base - 1],       c11 = cc[base],       c12 = cc[base + 1];
        float c20 = cc[base + LWX - 1], c21 = cc[base + LWX], c22 = cc[base + LWX + 1];
        p[c]      = c11;
        p[16 + c] = (c02 - c00 + 2.0f * (c12 - c10) + c22 - c20) * 0.125f;
        p[32 + c] = (c20 - c00 + 2.0f * (c21 - c01) + c22 - c02) * 0.125f;
    }
}

// ---------------- one fused CA step (MFMA matmuls, R8) ----------------
// R8 = R5 body (256-thr, fine granularity, 5 blocks/CU, 4-wave barriers)
// with R6's 32-wide tile (full 128-B global lines -> FETCH halved) and R6's
// fused init. R7's LDS store-bounce REVERTED (proved WRITE_SIZE is not an
// instruction-coalescing effect; bounce was pure overhead). Tile 32x8:
// cs 17x[12][36] = 29376 B; Ph [256][52] bf16 overlays. 2048 blocks.
__global__ __launch_bounds__(256, 5) void step_kernel(
    const float* __restrict__ inp, const float* __restrict__ cin,
    float* __restrict__ cout,
    const uint8_t* __restrict__ pre_in, uint8_t* __restrict__ pre_out,
    const unsigned short* __restrict__ w1h_, const unsigned short* __restrict__ w1l_,
    const unsigned short* __restrict__ w2h_, const unsigned short* __restrict__ w2l_,
    int gate, int first) {

    __shared__ __align__(16) char smem[SMEM_BYTES];
    float* cs = (float*)smem;                       // 17 planes x 432 floats
    unsigned short* Ph = (unsigned short*)smem;     // [256][PSTR] bf16 (overlays cs)

    const int tid = threadIdx.x;
    const int tx2 = tid & 31, ty2 = tid >> 5;       // pixel within 32x8 tile
    const int lane = tid & 63;
    const int wv = tid >> 6;            // wave id: pixels [64*wv, 64*wv+64) = rows 2wv,2wv+1
    const int px = lane & 15;           // col within 16-tile
    const int kc = lane >> 4;           // k-chunk id (0..3)

    // ---- XCD-aware decode: wgid%8 = XCD; each XCD owns 4 whole images ----
    const int wgid = blockIdx.x;
    const int xcd = wgid & 7;
    const int s   = wgid >> 3;              // 0..255 per XCD
    const int n   = (xcd << 2) + (s >> 6);  // image
    const int t_  = s & 63;                 // tile within image (4x16)
    const int bx = (t_ & 3) * TX;
    const int by = (t_ >> 2) * TY;

    const float* cbase = cin + (size_t)n * CH * HWSZ;
    const float* ibase = inp + (size_t)n * 10 * HWSZ;
    const uint8_t* pbase = pre_in + (size_t)n * HWSZ;

    // ---- hoisted coords: full 36x12 positions (raw ch0), two per thread ----
    const int lyA = tid / 36, lxA = tid % 36;
    const int gyA = by + lyA - 2, gxA = bx + lxA - 2;
    const bool okA = ((unsigned)gyA < HH) && ((unsigned)gxA < WW);
    const int offA = gyA * WW + gxA;

    const int rB = tid + 256;                  // valid when tid < 176 (432 total)
    const int lyB = rB / 36, lxB = rB % 36;
    const int gyB = by + lyB - 2, gxB = bx + lxB - 2;
    const bool okB = ((unsigned)gyB < HH) && ((unsigned)gxB < WW);
    const int offB = gyB * WW + gxB;
    const bool hasA2 = (tid < 176);

    // ---- hoisted coords: 34x10 gate-region positions, two per thread ----
    const int j0 = tid;                        // always < 340
    const int jy0 = j0 / 34, jx0 = j0 % 34;
    const int gy0 = by + jy0 - 1, gx0 = bx + jx0 - 1;
    const bool ok0 = ((unsigned)gy0 < HH) && ((unsigned)gx0 < WW);
    const int goff0 = gy0 * WW + gx0;
    const int lpos0 = (jy0 + 1) * LWX + (jx0 + 1);

    const int j1 = tid + 256;                  // valid when tid < 84 (340 total)
    const int jy1 = j1 / 34, jx1 = j1 % 34;
    const int gy1 = by + jy1 - 1, gx1 = bx + jx1 - 1;
    const bool ok1 = ((unsigned)gy1 < HH) && ((unsigned)gx1 < WW);
    const int goff1 = gy1 * WW + gx1;
    const int lpos1 = (jy1 + 1) * LWX + (jx1 + 1);
    const bool hasB = (tid < 84);

    // ---- A: stage raw ch0 (plane 16) AND pre-issue all global loads ----
    // first=1: read from inp with the init mapping (ch0 = 1-inp0).
    if (first) {
        cs[CH * LA + tid] = okA ? 1.0f - ibase[offA] : 0.0f;
        if (hasA2) cs[CH * LA + rB] = okB ? 1.0f - ibase[offB] : 0.0f;
    } else {
        cs[CH * LA + tid] = okA ? cbase[offA] : 0.0f;
        if (hasA2) cs[CH * LA + rB] = okB ? cbase[offB] : 0.0f;
    }

    float st0[CH - 1];
    float st1[CH - 1];
    int pv0 = 1, pv1 = 1;
    if (first) {
#pragma unroll
        for (int c = 1; c < CH; ++c)
            st0[c - 1] = (c <= 10 && ok0) ? ibase[(c - 1) * HWSZ + goff0] : 0.0f;
        if (hasB) {
#pragma unroll
            for (int c = 1; c < CH; ++c)
                st1[c - 1] = (c <= 10 && ok1) ? ibase[(c - 1) * HWSZ + goff1] : 0.0f;
        }
    } else {
        {
            const float* gp = cbase + goff0;
#pragma unroll
            for (int c = 1; c < CH; ++c) st0[c - 1] = ok0 ? gp[c * HWSZ] : 0.0f;
        }
        if (gate) pv0 = ok0 ? (int)pbase[goff0] : 0;
        if (hasB) {
            const float* gp = cbase + goff1;
#pragma unroll
            for (int c = 1; c < CH; ++c) st1[c - 1] = ok1 ? gp[c * HWSZ] : 0.0f;
            if (gate) pv1 = ok1 ? (int)pbase[goff1] : 0;
        }
    }
    __syncthreads();   // sync1

    // ---- B+C fused: gate from raw plane 16; gated writes to planes 0..15 ----
    {
        const float* rp = cs + CH * LA;
        float pm = max9(rp, lpos0, LWX);
        float g0 = 1.0f;
        if (gate) g0 = (pv0 && pm > THR) ? 1.0f : 0.0f;
        cs[lpos0] = rp[lpos0] * g0;
#pragma unroll
        for (int c = 1; c < CH; ++c) cs[c * LA + lpos0] = st0[c - 1] * g0;
    }
    if (hasB) {
        const float* rp = cs + CH * LA;
        float pm = max9(rp, lpos1, LWX);
        float g1 = 1.0f;
        if (gate) g1 = (pv1 && pm > THR) ? 1.0f : 0.0f;
        cs[lpos1] = rp[lpos1] * g1;
#pragma unroll
        for (int c = 1; c < CH; ++c) cs[c * LA + lpos1] = st1[c - 1] * g1;
    }
    __syncthreads();   // sync2

    // ---- D1: pre(i) bits + per-thread perception + residual grab (reads cs) ----
    const int base = (ty2 + 2) * LWX + (tx2 + 2);
    {
        float pm = max9(cs, base, LWX);
        pre_out[(size_t)n * HWSZ + (size_t)(by + ty2) * WW + (bx + tx2)] = (pm > THR) ? 1 : 0;
    }

    float p[48];
    perception_at(cs, base, p);

    // residual for this lane's D5 output assignment: pixel pix=64wv+16t+px,
    // channel 4kc+r -- gated fp32 state from cs, read before the Ph overlay.
    float res[4][4];
#pragma unroll
    for (int t = 0; t < 4; ++t) {
        const int pix = 64 * wv + 16 * t + px;
        const int lp = ((pix >> 5) + 2) * LWX + ((pix & 31) + 2);
#pragma unroll
        for (int r = 0; r < 4; ++r)
            res[t][r] = cs[(4 * kc + r) * LA + lp];
    }
    __syncthreads();   // sync3: all cs reads done; Ph may now overlay cs

    // ---- D2: p -> bf16 hi into LDS (row = tid = pixel; wave-private rows) ----
    {
        unsigned short* hrow = Ph + tid * PSTR;
#pragma unroll
        for (int j = 0; j < 12; ++j) {
            sh4 hv;
            hv.x = (short)f2bf(p[4 * j + 0]);
            hv.y = (short)f2bf(p[4 * j + 1]);
            hv.z = (short)f2bf(p[4 * j + 2]);
            hv.w = (short)f2bf(p[4 * j + 3]);
            *(sh4*)(hrow + 4 * j) = hv;
        }
    }
    // no barrier: D3 B-reads are wave-private rows, DS pipe in-order per wave

    // ---- D3: h = relu(w1 x P) via MFMA (2-product: (w1h+w1l) x Phi) ----
    const sh4 z4 = (sh4)0;
    const bf16x8 zero8 = mk8(z4, z4);

    f32x4 acc[3][4];
#pragma unroll
    for (int m = 0; m < 3; ++m)
#pragma unroll
        for (int t = 0; t < 4; ++t) acc[m][t] = 0.0f;

#pragma unroll
    for (int m = 0; m < 3; ++m) {
        const unsigned short* ah = w1h_ + (16 * m + px) * 48;
        const unsigned short* al = w1l_ + (16 * m + px) * 48;
        bf16x8 Ah1 = mk8(ld4(ah + 8 * kc), ld4(ah + 8 * kc + 4));
        bf16x8 Ah2 = mk8(ld4(ah + 32 + 8 * kc), ld4(ah + 36 + 8 * kc));  // padded buf; garbage for kc>=2 ok (B=0)
        bf16x8 Al1 = mk8(ld4(al + 8 * kc), ld4(al + 8 * kc + 4));
        bf16x8 Al2 = mk8(ld4(al + 32 + 8 * kc), ld4(al + 36 + 8 * kc));
#pragma unroll
        for (int t = 0; t < 4; ++t) {
            const int pix = 64 * wv + 16 * t + px;
            const unsigned short* bh = Ph + pix * PSTR;
            bf16x8 Bh1 = mk8(ld4(bh + 8 * kc), ld4(bh + 8 * kc + 4));
            bf16x8 Bh2 = (kc < 2) ? mk8(ld4(bh + 32 + 8 * kc), ld4(bh + 36 + 8 * kc)) : zero8;
            f32x4 a = acc[m][t];
            a = __builtin_amdgcn_mfma_f32_16x16x32_bf16(Al1, Bh1, a, 0, 0, 0);
            a = __builtin_amdgcn_mfma_f32_16x16x32_bf16(Al2, Bh2, a, 0, 0, 0);
            a = __builtin_amdgcn_mfma_f32_16x16x32_bf16(Ah1, Bh1, a, 0, 0, 0);
            a = __builtin_amdgcn_mfma_f32_16x16x32_bf16(Ah2, Bh2, a, 0, 0, 0);
            acc[m][t] = a;
        }
    }
    // no barrier: D4 writes the same wave-private rows D3 just read

    // ---- D4: h = relu(acc) -> bf16, overlaying Ph. lane holds q=16m+4kc+r ----
#pragma unroll
    for (int t = 0; t < 4; ++t) {
        const int pix = 64 * wv + 16 * t + px;
        unsigned short* hrow = Ph + pix * PSTR;
#pragma unroll
        for (int m = 0; m < 3; ++m) {
            f32x4 a = acc[m][t];
            sh4 hv;
            hv.x = (short)f2bf(fmaxf(a[0], 0.0f));
            hv.y = (short)f2bf(fmaxf(a[1], 0.0f));
            hv.z = (short)f2bf(fmaxf(a[2], 0.0f));
            hv.w = (short)f2bf(fmaxf(a[3], 0.0f));
            *(sh4*)(hrow + 16 * m + 4 * kc) = hv;
        }
    }
    // no barrier: D5 reads the same wave-private rows

    // ---- D5: cur = (w2h+w2l) x H + res; direct scalar stores (R7 bounce reverted) ----
    {
        const unsigned short* ah = w2h_ + px * 48;
        const unsigned short* al = w2l_ + px * 48;
        bf16x8 A2h1 = mk8(ld4(ah + 8 * kc), ld4(ah + 8 * kc + 4));
        bf16x8 A2h2 = mk8(ld4(ah + 32 + 8 * kc), ld4(ah + 36 + 8 * kc));
        bf16x8 A2l1 = mk8(ld4(al + 8 * kc), ld4(al + 8 * kc + 4));
        bf16x8 A2l2 = mk8(ld4(al + 32 + 8 * kc), ld4(al + 36 + 8 * kc));

        f32x4 q[4];
#pragma unroll
        for (int t = 0; t < 4; ++t) q[t] = 0.0f;
#pragma unroll
        for (int t = 0; t < 4; ++t) {
            const int pix = 64 * wv + 16 * t + px;
            const unsigned short* bh = Ph + pix * PSTR;
            bf16x8 B1 = mk8(ld4(bh + 8 * kc), ld4(bh + 8 * kc + 4));
            bf16x8 B2 = (kc < 2) ? mk8(ld4(bh + 32 + 8 * kc), ld4(bh + 36 + 8 * kc)) : zero8;
            f32x4 a = q[t];
            a = __builtin_amdgcn_mfma_f32_16x16x32_bf16(A2l1, B1, a, 0, 0, 0);
            a = __builtin_amdgcn_mfma_f32_16x16x32_bf16(A2l2, B2, a, 0, 0, 0);
            a = __builtin_amdgcn_mfma_f32_16x16x32_bf16(A2h1, B1, a, 0, 0, 0);
            a = __builtin_amdgcn_mfma_f32_16x16x32_bf16(A2h2, B2, a, 0, 0, 0);
            q[t] = a;
        }

        float* ob = cout + (size_t)n * CH * HWSZ;
#pragma unroll
        for (int t = 0; t < 4; ++t) {
            const int pix = 64 * wv + 16 * t + px;
            const int rowoff = (by + (pix >> 5)) * WW + bx + (pix & 31);
#pragma unroll
            for (int r = 0; r < 4; ++r)
                ob[(size_t)(4 * kc + r) * HWSZ + rowoff] = q[t][r] + res[t][r];
        }
    }
}

// ---------------- final: apply gate(30), emit channels 1..10 ----------------
__global__ __launch_bounds__(256) void final_kernel(
    const float* __restrict__ cur, const uint8_t* __restrict__ pre,
    float* __restrict__ out) {
    int i = blockIdx.x * 256 + threadIdx.x;        // over NIMG*H*W
    if (i >= NIMG * HWSZ) return;
    int x = i % WW, y = (i / WW) % HH, n = i / HWSZ;
    const float* c0 = cur + (size_t)n * CH * HWSZ;
    float pm = -1e30f;
    for (int dy = -1; dy <= 1; ++dy) {
        int yy = y + dy;
        if ((unsigned)yy >= HH) continue;
        for (int dx = -1; dx <= 1; ++dx) {
            int xx = x + dx;
            if ((unsigned)xx >= WW) continue;
            pm = fmaxf(pm, c0[yy * WW + xx]);
        }
    }
    const bool alive = pre[i] && (pm > THR);
    float* ob = out + (size_t)n * 10 * HWSZ + y * WW + x;
#pragma unroll
    for (int k = 1; k <= 10; ++k)
        ob[(k - 1) * HWSZ] = alive ? c0[k * HWSZ + y * WW + x] : 0.0f;
}

extern "C" void kernel_launch(void* const* d_in, const int* in_sizes, int n_in,
                              void* d_out, int out_size, void* d_ws, size_t ws_size,
                              hipStream_t stream) {
    const float* inp = (const float*)d_in[0];
    const float* w1  = (const float*)d_in[1];
    const float* w2  = (const float*)d_in[2];
    float* out = (float*)d_out;

    const size_t SE = (size_t)NIMG * CH * HWSZ;    // 8,388,608 floats
    float* bufA = (float*)d_ws;
    float* bufB = bufA + SE;
    uint8_t* bitsA = (uint8_t*)(bufB + SE);
    uint8_t* bitsB = bitsA + (size_t)NIMG * HWSZ;
    // weight fragments (bf16), padded +32 shorts so chunk-2 A reads stay in-bounds
    unsigned short* w1h = (unsigned short*)(bitsB + (size_t)NIMG * HWSZ);
    unsigned short* w1l = w1h + (48 * 48 + 32);
    unsigned short* w2h = w1l + (48 * 48 + 32);
    unsigned short* w2l = w2h + (16 * 48 + 32);

    prepack<<<1, 256, 0, stream>>>(w1, w2, w1h, w1l, w2h, w2l);

    const int nblk = NIMG * (HH / TY) * (WW / TX);   // 2048, 1-D swizzled grid
    float* src = bufB;      // dummy on first iter (first=1 reads inp)
    float* dst = bufA;
    uint8_t* pin = bitsB;   // unused on first iter (gate=0)
    uint8_t* pout = bitsA;
    for (int it = 0; it < NUM_ITER; ++it) {
        step_kernel<<<nblk, 256, 0, stream>>>(inp, src, dst, pin, pout,
                                              w1h, w1l, w2h, w2l,
                                              it == 0 ? 0 : 1, it == 0 ? 1 : 0);
        float* t = src; src = dst; dst = t;
        uint8_t* tb = pin; pin = pout; pout = tb;
    }
    // after loop: src = cur(30), pin = pre(30) bits
    final_kernel<<<(NIMG * HWSZ + 255) / 256, 256, 0, stream>>>(src, pin, out);
}